// Round 3
// baseline (232.711 us; speedup 1.0000x reference)
//
#include <hip/hip_runtime.h>
#include <hip/hip_bf16.h>
#include <stdint.h>

// GCN on MI355X. ALL I/O IS FLOAT32.
//   out0 = relu( (D^-1/2 A D^-1/2) @ (graph @ W) + bias )   [16,4096,64] fp32
//   out1 = adj (verbatim fp32 copy)                          [4096,4096] fp32
// r3: revert to the proven 128x128 / 4-blocks-per-CU structure (r0, 222us;
// both 256x256 1-block/CU pipelines regressed ~+9us: data is L2/L3-resident
// so there is no HBM stall to hide, and 8-wave barrier sync loses to
// cross-block overlap). Single change vs r0: inner MFMA 16x16x32 ->
// 32x32x16 (same frag reg counts, -20% matrix-pipe cycles, -50% MFMA issue,
// fewer live VGPRs under the (256,4) cap). Staging, swizzle, barriers,
// grid identical to r0.

typedef __bf16 bf16;
typedef __bf16 bf16x4 __attribute__((ext_vector_type(4)));
typedef __bf16 bf16x8 __attribute__((ext_vector_type(8)));
typedef float f32x4 __attribute__((ext_vector_type(4)));
typedef float f32x16 __attribute__((ext_vector_type(16)));

#define NN 4096
#define BATCH 16
#define FD 64
#define CDIM 1024   // BATCH*FD

// ---------- Kernel 1: adj -> bf16 + rowsum -> dsq ; optional fused out1 copy ----------
__global__ __launch_bounds__(256) void k_prep(const float* __restrict__ adj,
                                              bf16* __restrict__ adjb,
                                              float* __restrict__ dsq,
                                              float4* __restrict__ out1,
                                              int do_copy) {
    int row = blockIdx.x;
    const float4* p = (const float4*)(adj + (size_t)row * NN);  // 1024 x float4
    uint4* q = (uint4*)(adjb + (size_t)row * NN);               // 512 x (8 bf16)
    float4* o = out1 + (size_t)row * (NN / 4);
    float s = 0.f;
    for (int j = threadIdx.x; j < 512; j += 256) {
        float4 a = p[2 * j], b = p[2 * j + 1];
        if (do_copy) { o[2 * j] = a; o[2 * j + 1] = b; }
        bf16x8 h;
        h[0] = (bf16)a.x; h[1] = (bf16)a.y; h[2] = (bf16)a.z; h[3] = (bf16)a.w;
        h[4] = (bf16)b.x; h[5] = (bf16)b.y; h[6] = (bf16)b.z; h[7] = (bf16)b.w;
        q[j] = __builtin_bit_cast(uint4, h);
        s += a.x + a.y + a.z + a.w + b.x + b.y + b.z + b.w;
    }
    #pragma unroll
    for (int off = 32; off > 0; off >>= 1) s += __shfl_down(s, off, 64);
    __shared__ float red[4];
    int lane = threadIdx.x & 63, wv = threadIdx.x >> 6;
    if (lane == 0) red[wv] = s;
    __syncthreads();
    if (threadIdx.x == 0) {
        float t = red[0] + red[1] + red[2] + red[3];
        if (t == 0.f) t = 1.f;              // isolated-node guard (ref semantics)
        dsq[row] = 1.0f / sqrtf(t);
    }
}

// ---------- Kernel 2: spT[c=b*64+o][m] = dsq[m] * sum_i graph[b,m,i]*W[i,o] ----------
__global__ __launch_bounds__(256) void k_support(const float* __restrict__ graph,
                                                 const float* __restrict__ weight,
                                                 const float* __restrict__ dsq,
                                                 bf16* __restrict__ spT) {
    __shared__ float wT[64 * 64];           // wT[o*64+i]
    int tid = threadIdx.x;
    for (int idx = tid; idx < 4096; idx += 256) {
        int i = idx >> 6, o = idx & 63;
        wT[o * 64 + i] = weight[idx];
    }
    __syncthreads();
    int b = blockIdx.y;
    int m = blockIdx.x * 256 + tid;
    const float4* g4 = (const float4*)(graph + ((size_t)b * NN + m) * FD);
    float ds = dsq[m];
    float gr[64];
    #pragma unroll
    for (int j = 0; j < 16; j++) {
        float4 v = g4[j];
        gr[4 * j] = v.x * ds; gr[4 * j + 1] = v.y * ds;
        gr[4 * j + 2] = v.z * ds; gr[4 * j + 3] = v.w * ds;
    }
    bf16* outp = spT + m;
    for (int o = 0; o < 64; o++) {
        const float4* w4 = (const float4*)&wT[o * 64];
        float acc = 0.f;
        #pragma unroll
        for (int j = 0; j < 16; j++) {
            float4 wv = w4[j];
            acc += gr[4 * j] * wv.x + gr[4 * j + 1] * wv.y
                 + gr[4 * j + 2] * wv.z + gr[4 * j + 3] * wv.w;
        }
        outp[(size_t)(b * 64 + o) * NN] = (bf16)acc;
    }
}

// ---------- Kernel 3: part_z[n][c] = bf16( dsq[n] * sum_{chunk z} adjb[n][m]*spT[c][m] ) ----------
// grid (32, 8, nsplit). 128x128 tile, BK=64, global_load_lds(16B) staging with
// global-side swizzle, 32x32x16 bf16 MFMA, 2 barriers per 64-k step.
__global__ __launch_bounds__(256, 4) void k_gemm(const bf16* __restrict__ adjb,
                                                 const bf16* __restrict__ spT,
                                                 const float* __restrict__ dsq,
                                                 bf16* __restrict__ part,
                                                 int kchunk) {
    __shared__ bf16x8 lds_a[1024];  // A: 128 rows x 64 k; chunk g=(row*8+sub),
    __shared__ bf16x8 lds_b[1024];  //   holds global sub' = sub ^ (row&7)
    const int tid = threadIdx.x;
    const int lane = tid & 63;
    const int w = tid >> 6;
    const int n0 = blockIdx.x * 128;
    const int c0 = blockIdx.y * 128;
    const size_t kbase = (size_t)blockIdx.z * kchunk;
    const int niter = kchunk >> 6;
    bf16* __restrict__ pp = part + (size_t)blockIdx.z * NN * CDIM;

    // Staging: per wave 4 A + 4 B instructions, each 64 lanes x 16B = 1KB.
    // Instruction j covers LDS chunks [(w*4+j)*64, +64); lane supplies the
    // global address of the swizzled sub-chunk that lands at its slot.
    const bf16* gA[4]; const bf16* gB[4];
    bf16x8* lA[4]; bf16x8* lB[4];
    #pragma unroll
    for (int j = 0; j < 4; j++) {
        int g = (w * 4 + j) * 64 + lane;
        int row = g >> 3;
        int sub = (g & 7) ^ (row & 7);      // global-side swizzle
        gA[j] = adjb + (size_t)(n0 + row) * NN + kbase + sub * 8;
        gB[j] = spT  + (size_t)(c0 + row) * NN + kbase + sub * 8;
        lA[j] = &lds_a[(w * 4 + j) * 64];
        lB[j] = &lds_b[(w * 4 + j) * 64];
    }

    // 32x32x16 fragments. Wave sub-tile 64x64 at (rm, rc) = 2x2 of 32x32.
    // A: lane holds row (lane&31), k = (lane>>5)*8 + j  -> global sub-chunk
    // within the 64-k tile for kstep ks: sub = 2*ks + (lane>>5).
    // Stored chunk index = row*8 + (sub ^ (row&7)).
    const int rm = (w >> 1) * 64, rc = (w & 1) * 64;
    const int l31 = lane & 31, qo2 = lane >> 5;
    const int RA0 = rm + l31,      RA1 = rm + 32 + l31;
    const int RB0 = rc + l31,      RB1 = rc + 32 + l31;
    const int ba0 = RA0 * 8, ma0 = RA0 & 7;
    const int ba1 = RA1 * 8, ma1 = RA1 & 7;
    const int bb0 = RB0 * 8, mb0 = RB0 & 7;
    const int bb1 = RB1 * 8, mb1 = RB1 & 7;

    f32x16 ac[2][2];
    #pragma unroll
    for (int i = 0; i < 2; i++)
        #pragma unroll
        for (int j = 0; j < 2; j++)
            #pragma unroll
            for (int e = 0; e < 16; e++)
                ac[i][j][e] = 0.f;

    for (int it = 0; it < niter; it++) {
        const int kt = it * 64;
        __syncthreads();                    // prior iter's LDS reads done
        #pragma unroll
        for (int j = 0; j < 4; j++) {
            __builtin_amdgcn_global_load_lds(
                (const __attribute__((address_space(1))) void*)(gA[j] + kt),
                (__attribute__((address_space(3))) void*)lA[j], 16, 0, 0);
            __builtin_amdgcn_global_load_lds(
                (const __attribute__((address_space(1))) void*)(gB[j] + kt),
                (__attribute__((address_space(3))) void*)lB[j], 16, 0, 0);
        }
        __syncthreads();                    // vmcnt drained before barrier
        #pragma unroll
        for (int ks = 0; ks < 4; ks++) {
            const int sub = 2 * ks + qo2;
            bf16x8 a0 = lds_a[ba0 + (sub ^ ma0)];
            bf16x8 a1 = lds_a[ba1 + (sub ^ ma1)];
            bf16x8 b0 = lds_b[bb0 + (sub ^ mb0)];
            bf16x8 b1 = lds_b[bb1 + (sub ^ mb1)];
            ac[0][0] = __builtin_amdgcn_mfma_f32_32x32x16_bf16(a0, b0, ac[0][0], 0, 0, 0);
            ac[0][1] = __builtin_amdgcn_mfma_f32_32x32x16_bf16(a0, b1, ac[0][1], 0, 0, 0);
            ac[1][0] = __builtin_amdgcn_mfma_f32_32x32x16_bf16(a1, b0, ac[1][0], 0, 0, 0);
            ac[1][1] = __builtin_amdgcn_mfma_f32_32x32x16_bf16(a1, b1, ac[1][1], 0, 0, 0);
        }
    }

    // Store bf16 partial with dsq[n] folded.
    // C/D layout (m74/m101): col = lane&31, row = (reg&3) + 8*(reg>>2) + 4*(lane>>5).
    // n = n0 + rm + mi*32 + row ; c = c0 + rc + ni*32 + (lane&31)
    #pragma unroll
    for (int mi = 0; mi < 2; mi++) {
        #pragma unroll
        for (int rq = 0; rq < 4; rq++) {
            const int nb = n0 + rm + mi * 32 + rq * 8 + 4 * qo2;
            float4 dq = *(const float4*)&dsq[nb];
            float dqa[4] = {dq.x, dq.y, dq.z, dq.w};
            #pragma unroll
            for (int ni = 0; ni < 2; ni++) {
                const int c = c0 + rc + ni * 32 + l31;
                #pragma unroll
                for (int j = 0; j < 4; j++) {
                    pp[(size_t)(nb + j) * CDIM + c] =
                        (bf16)(dqa[j] * ac[mi][ni][rq * 4 + j]);
                }
            }
        }
    }
}

// ---------- Kernel 4: out0[b,n,o] = relu(sum_z part_z[n][b*64+o] + bias[o]) ----------
__global__ __launch_bounds__(256) void k_epi(const bf16* __restrict__ part,
                                             int nsplit,
                                             const float* __restrict__ bias,
                                             float4* __restrict__ out0) {
    int idx = blockIdx.x * 256 + threadIdx.x;       // 1,048,576 x (4 floats)
    int flat = idx * 4;
    int o4 = flat & 63;
    int n = (flat >> 6) & (NN - 1);
    int b = flat >> 18;                             // 4096*64 = 1<<18
    size_t off = (size_t)n * CDIM + b * 64 + o4;    // element offset, %4==0
    const size_t zstride = (size_t)NN * CDIM;
    float ax = 0.f, ay = 0.f, az = 0.f, aw = 0.f;
    for (int z = 0; z < nsplit; z++) {
        bf16x4 t = *(const bf16x4*)(part + off + z * zstride);
        ax += (float)t[0]; ay += (float)t[1]; az += (float)t[2]; aw += (float)t[3];
    }
    float4 bv = *(const float4*)(bias + o4);
    float4 r;
    r.x = fmaxf(ax + bv.x, 0.f);
    r.y = fmaxf(ay + bv.y, 0.f);
    r.z = fmaxf(az + bv.z, 0.f);
    r.w = fmaxf(aw + bv.w, 0.f);
    out0[idx] = r;
}

// ---------- Kernel 5: adj -> out1 fp32 copy (fallback path only, runs LAST) ----------
__global__ __launch_bounds__(256) void k_copy(const float4* __restrict__ src,
                                              float4* __restrict__ dst) {
    size_t i = (size_t)blockIdx.x * 256 + threadIdx.x;
    dst[i] = src[i];
}

extern "C" void kernel_launch(void* const* d_in, const int* in_sizes, int n_in,
                              void* d_out, int out_size, void* d_ws, size_t ws_size,
                              hipStream_t stream) {
    const float *graph = nullptr, *adj = nullptr, *weight = nullptr, *bias = nullptr;
    for (int i = 0; i < n_in; i++) {
        const float* p = (const float*)d_in[i];
        switch (in_sizes[i]) {
            case BATCH * NN * FD: graph  = p; break;   // 4,194,304
            case NN * NN:         adj    = p; break;   // 16,777,216
            case FD * FD:         weight = p; break;   // 4,096
            case FD:              bias   = p; break;   // 64
        }
    }

    float* out0 = (float*)d_out;                       // [16,4096,64] fp32 (16.8MB)
    float* out1 = out0 + (size_t)BATCH * NN * FD;      // [4096,4096] fp32 (67MB)

    const size_t SZ_ADJB = (size_t)NN * NN * 2;            // 32 MiB
    const size_t SZ_SPT  = (size_t)CDIM * NN * 2;          // 8 MiB
    const size_t SZ_DSQ  = (size_t)NN * 4;                 // 16 KiB
    const size_t SZ_PART = (size_t)NN * CDIM * 2;          // 8.4 MiB per split (bf16)

    bf16 *adjb, *spT, *part; float *dsq;
    int nsplit, do_copy_in_prep;
    if (ws_size >= SZ_ADJB + SZ_SPT + SZ_DSQ + 4 * SZ_PART) {
        nsplit = 4; do_copy_in_prep = 1;
        char* s = (char*)d_ws;
        adjb = (bf16*)s;
        spT  = (bf16*)(s + SZ_ADJB);
        dsq  = (float*)(s + SZ_ADJB + SZ_SPT);
        part = (bf16*)(s + SZ_ADJB + SZ_SPT + SZ_DSQ);
    } else if (ws_size >= SZ_ADJB + SZ_SPT + SZ_DSQ + 2 * SZ_PART) {
        nsplit = 2; do_copy_in_prep = 1;
        char* s = (char*)d_ws;
        adjb = (bf16*)s;
        spT  = (bf16*)(s + SZ_ADJB);
        dsq  = (float*)(s + SZ_ADJB + SZ_SPT);
        part = (bf16*)(s + SZ_ADJB + SZ_SPT + SZ_DSQ);
    } else {
        // Carve: out1 = [part 4x8.4MB | adjb 32MB] (~66MB of 67MB);
        //        out0 = [spT 8MB | dsq 16KB] (consumed before k_epi writes out0).
        nsplit = 4; do_copy_in_prep = 0;
        part = (bf16*)out1;
        adjb = (bf16*)((char*)out1 + 4 * SZ_PART);
        spT  = (bf16*)out0;
        dsq  = (float*)((char*)out0 + SZ_SPT);
    }
    const int kchunk = NN / nsplit;

    hipLaunchKernelGGL(k_prep, dim3(NN), dim3(256), 0, stream,
                       adj, adjb, dsq, (float4*)out1, do_copy_in_prep);
    hipLaunchKernelGGL(k_support, dim3(16, 16), dim3(256), 0, stream,
                       graph, weight, dsq, spT);
    hipLaunchKernelGGL(k_gemm, dim3(32, 8, nsplit), dim3(256), 0, stream,
                       adjb, spT, dsq, part, kchunk);
    hipLaunchKernelGGL(k_epi, dim3(4096), dim3(256), 0, stream,
                       part, nsplit, bias, (float4*)out0);
    if (!do_copy_in_prep) {
        hipLaunchKernelGGL(k_copy, dim3(16384), dim3(256), 0, stream,
                           (const float4*)adj, (float4*)out1);
    }
}

// Round 4
// 223.941 us; speedup vs baseline: 1.0392x; 1.0392x over previous
//
#include <hip/hip_runtime.h>
#include <hip/hip_bf16.h>
#include <stdint.h>

// GCN on MI355X. ALL I/O IS FLOAT32.
//   out0 = relu( (D^-1/2 A D^-1/2) @ (graph @ W) + bias )   [16,4096,64] fp32
//   out1 = adj (verbatim fp32 copy)                          [4096,4096] fp32
// r4: REVERT to r0 (session best, 222.2us; prev session 228.5us).
// r1/r2 (256x256 pipelined, drain-0 and counted-vmcnt) both ~+9us: data is
// L2/L3-resident so there is no HBM stall to amortize, and 1-block/CU
// 8-wave lockstep loses to 4-blocks/CU cross-block overlap (m114).
// r3 (32x32x16 MFMA) +10us: MFMA issue bandwidth was not the limiter.
// k_gemm: bf16 MFMA 128x128 tile, BK=64, K-split (per-z bf16 partials,
// no atomics), global_load_lds width=16 staging with global-side swizzle
// sub^=(row&7) -> linear LDS writes, conflict-free b128 reads.

typedef __bf16 bf16;
typedef __bf16 bf16x4 __attribute__((ext_vector_type(4)));
typedef __bf16 bf16x8 __attribute__((ext_vector_type(8)));
typedef float f32x4 __attribute__((ext_vector_type(4)));

#define NN 4096
#define BATCH 16
#define FD 64
#define CDIM 1024   // BATCH*FD

// ---------- Kernel 1: adj -> bf16 + rowsum -> dsq ; optional fused out1 copy ----------
__global__ __launch_bounds__(256) void k_prep(const float* __restrict__ adj,
                                              bf16* __restrict__ adjb,
                                              float* __restrict__ dsq,
                                              float4* __restrict__ out1,
                                              int do_copy) {
    int row = blockIdx.x;
    const float4* p = (const float4*)(adj + (size_t)row * NN);  // 1024 x float4
    uint4* q = (uint4*)(adjb + (size_t)row * NN);               // 512 x (8 bf16)
    float4* o = out1 + (size_t)row * (NN / 4);
    float s = 0.f;
    for (int j = threadIdx.x; j < 512; j += 256) {
        float4 a = p[2 * j], b = p[2 * j + 1];
        if (do_copy) { o[2 * j] = a; o[2 * j + 1] = b; }
        bf16x8 h;
        h[0] = (bf16)a.x; h[1] = (bf16)a.y; h[2] = (bf16)a.z; h[3] = (bf16)a.w;
        h[4] = (bf16)b.x; h[5] = (bf16)b.y; h[6] = (bf16)b.z; h[7] = (bf16)b.w;
        q[j] = __builtin_bit_cast(uint4, h);
        s += a.x + a.y + a.z + a.w + b.x + b.y + b.z + b.w;
    }
    #pragma unroll
    for (int off = 32; off > 0; off >>= 1) s += __shfl_down(s, off, 64);
    __shared__ float red[4];
    int lane = threadIdx.x & 63, wv = threadIdx.x >> 6;
    if (lane == 0) red[wv] = s;
    __syncthreads();
    if (threadIdx.x == 0) {
        float t = red[0] + red[1] + red[2] + red[3];
        if (t == 0.f) t = 1.f;              // isolated-node guard (ref semantics)
        dsq[row] = 1.0f / sqrtf(t);
    }
}

// ---------- Kernel 2: spT[c=b*64+o][m] = dsq[m] * sum_i graph[b,m,i]*W[i,o] ----------
__global__ __launch_bounds__(256) void k_support(const float* __restrict__ graph,
                                                 const float* __restrict__ weight,
                                                 const float* __restrict__ dsq,
                                                 bf16* __restrict__ spT) {
    __shared__ float wT[64 * 64];           // wT[o*64+i]
    int tid = threadIdx.x;
    for (int idx = tid; idx < 4096; idx += 256) {
        int i = idx >> 6, o = idx & 63;
        wT[o * 64 + i] = weight[idx];
    }
    __syncthreads();
    int b = blockIdx.y;
    int m = blockIdx.x * 256 + tid;
    const float4* g4 = (const float4*)(graph + ((size_t)b * NN + m) * FD);
    float ds = dsq[m];
    float gr[64];
    #pragma unroll
    for (int j = 0; j < 16; j++) {
        float4 v = g4[j];
        gr[4 * j] = v.x * ds; gr[4 * j + 1] = v.y * ds;
        gr[4 * j + 2] = v.z * ds; gr[4 * j + 3] = v.w * ds;
    }
    bf16* outp = spT + m;
    for (int o = 0; o < 64; o++) {
        const float4* w4 = (const float4*)&wT[o * 64];
        float acc = 0.f;
        #pragma unroll
        for (int j = 0; j < 16; j++) {
            float4 wv = w4[j];
            acc += gr[4 * j] * wv.x + gr[4 * j + 1] * wv.y
                 + gr[4 * j + 2] * wv.z + gr[4 * j + 3] * wv.w;
        }
        outp[(size_t)(b * 64 + o) * NN] = (bf16)acc;
    }
}

// ---------- Kernel 3: part_z[n][c] = bf16( dsq[n] * sum_{chunk z} adjb[n][m]*spT[c][m] ) ----------
// grid (32, 8, nsplit). 128x128 tile, BK=64, global_load_lds(16B) staging with
// global-side swizzle, 16x16x32 bf16 MFMA, 2 barriers per 64-k step.
__global__ __launch_bounds__(256, 4) void k_gemm(const bf16* __restrict__ adjb,
                                                 const bf16* __restrict__ spT,
                                                 const float* __restrict__ dsq,
                                                 bf16* __restrict__ part,
                                                 int kchunk) {
    __shared__ bf16x8 lds_a[1024];  // A: 128 rows x 64 k; chunk g=(row*8+sub),
    __shared__ bf16x8 lds_b[1024];  //   holds global sub' = sub ^ (row&7)
    const int tid = threadIdx.x;
    const int lane = tid & 63;
    const int w = tid >> 6;
    const int n0 = blockIdx.x * 128;
    const int c0 = blockIdx.y * 128;
    const size_t kbase = (size_t)blockIdx.z * kchunk;
    const int niter = kchunk >> 6;
    bf16* __restrict__ pp = part + (size_t)blockIdx.z * NN * CDIM;

    // Staging: per wave 4 A + 4 B instructions, each 64 lanes x 16B = 1KB.
    // Instruction j covers LDS chunks [(w*4+j)*64, +64); lane supplies the
    // global address of the swizzled sub-chunk that lands at its slot.
    const bf16* gA[4]; const bf16* gB[4];
    bf16x8* lA[4]; bf16x8* lB[4];
    #pragma unroll
    for (int j = 0; j < 4; j++) {
        int g = (w * 4 + j) * 64 + lane;
        int row = g >> 3;
        int sub = (g & 7) ^ (row & 7);      // global-side swizzle
        gA[j] = adjb + (size_t)(n0 + row) * NN + kbase + sub * 8;
        gB[j] = spT  + (size_t)(c0 + row) * NN + kbase + sub * 8;
        lA[j] = &lds_a[(w * 4 + j) * 64];
        lB[j] = &lds_b[(w * 4 + j) * 64];
    }

    const int r = lane & 15, qo = lane >> 4;
    const int rm = (w >> 1) * 64, rc = (w & 1) * 64;   // 64x64 sub-tile per wave
    const int rowA = rm + r, rowB = rc + r;
    // Fragment base for k-half kk: chunk = row*8 + ((kk*4+qo) ^ (row&7));
    // mi/ni step = 16 rows = 128 chunks (XOR term invariant: 16%8==0).
    const bf16x8* fA0 = lds_a + rowA * 8 + ((qo)     ^ (rowA & 7));
    const bf16x8* fA1 = lds_a + rowA * 8 + ((4 + qo) ^ (rowA & 7));
    const bf16x8* fB0 = lds_b + rowB * 8 + ((qo)     ^ (rowB & 7));
    const bf16x8* fB1 = lds_b + rowB * 8 + ((4 + qo) ^ (rowB & 7));

    f32x4 ac[4][4];
    #pragma unroll
    for (int i = 0; i < 4; i++)
        #pragma unroll
        for (int j = 0; j < 4; j++)
            ac[i][j] = (f32x4){0.f, 0.f, 0.f, 0.f};

    for (int it = 0; it < niter; it++) {
        const int kt = it * 64;
        __syncthreads();                    // prior iter's LDS reads done
        #pragma unroll
        for (int j = 0; j < 4; j++) {
            __builtin_amdgcn_global_load_lds(
                (const __attribute__((address_space(1))) void*)(gA[j] + kt),
                (__attribute__((address_space(3))) void*)lA[j], 16, 0, 0);
            __builtin_amdgcn_global_load_lds(
                (const __attribute__((address_space(1))) void*)(gB[j] + kt),
                (__attribute__((address_space(3))) void*)lB[j], 16, 0, 0);
        }
        __syncthreads();                    // vmcnt drained before barrier
        // k-half 0
        {
            bf16x8 af[4], bfr[4];
            #pragma unroll
            for (int mi = 0; mi < 4; mi++) af[mi] = fA0[mi * 128];
            #pragma unroll
            for (int ni = 0; ni < 4; ni++) bfr[ni] = fB0[ni * 128];
            #pragma unroll
            for (int mi = 0; mi < 4; mi++)
                #pragma unroll
                for (int ni = 0; ni < 4; ni++)
                    ac[mi][ni] = __builtin_amdgcn_mfma_f32_16x16x32_bf16(
                        af[mi], bfr[ni], ac[mi][ni], 0, 0, 0);
        }
        // k-half 1
        {
            bf16x8 af[4], bfr[4];
            #pragma unroll
            for (int mi = 0; mi < 4; mi++) af[mi] = fA1[mi * 128];
            #pragma unroll
            for (int ni = 0; ni < 4; ni++) bfr[ni] = fB1[ni * 128];
            #pragma unroll
            for (int mi = 0; mi < 4; mi++)
                #pragma unroll
                for (int ni = 0; ni < 4; ni++)
                    ac[mi][ni] = __builtin_amdgcn_mfma_f32_16x16x32_bf16(
                        af[mi], bfr[ni], ac[mi][ni], 0, 0, 0);
        }
    }

    // Store bf16 partial with dsq[n] folded. c = c0+rc+ni*16+r, n = n0+rm+mi*16+qo*4+rr
    #pragma unroll
    for (int mi = 0; mi < 4; mi++) {
        float dn[4];
        #pragma unroll
        for (int rr = 0; rr < 4; rr++) dn[rr] = dsq[n0 + rm + mi * 16 + qo * 4 + rr];
        #pragma unroll
        for (int ni = 0; ni < 4; ni++) {
            int c = c0 + rc + ni * 16 + r;
            #pragma unroll
            for (int rr = 0; rr < 4; rr++) {
                int n = n0 + rm + mi * 16 + qo * 4 + rr;
                pp[(size_t)n * CDIM + c] = (bf16)(dn[rr] * ac[mi][ni][rr]);
            }
        }
    }
}

// ---------- Kernel 4: out0[b,n,o] = relu(sum_z part_z[n][b*64+o] + bias[o]) ----------
__global__ __launch_bounds__(256) void k_epi(const bf16* __restrict__ part,
                                             int nsplit,
                                             const float* __restrict__ bias,
                                             float4* __restrict__ out0) {
    int idx = blockIdx.x * 256 + threadIdx.x;       // 1,048,576 x (4 floats)
    int flat = idx * 4;
    int o4 = flat & 63;
    int n = (flat >> 6) & (NN - 1);
    int b = flat >> 18;                             // 4096*64 = 1<<18
    size_t off = (size_t)n * CDIM + b * 64 + o4;    // element offset, %4==0
    const size_t zstride = (size_t)NN * CDIM;
    float ax = 0.f, ay = 0.f, az = 0.f, aw = 0.f;
    for (int z = 0; z < nsplit; z++) {
        bf16x4 t = *(const bf16x4*)(part + off + z * zstride);
        ax += (float)t[0]; ay += (float)t[1]; az += (float)t[2]; aw += (float)t[3];
    }
    float4 bv = *(const float4*)(bias + o4);
    float4 r;
    r.x = fmaxf(ax + bv.x, 0.f);
    r.y = fmaxf(ay + bv.y, 0.f);
    r.z = fmaxf(az + bv.z, 0.f);
    r.w = fmaxf(aw + bv.w, 0.f);
    out0[idx] = r;
}

// ---------- Kernel 5: adj -> out1 fp32 copy (fallback path only, runs LAST) ----------
__global__ __launch_bounds__(256) void k_copy(const float4* __restrict__ src,
                                              float4* __restrict__ dst) {
    size_t i = (size_t)blockIdx.x * 256 + threadIdx.x;
    dst[i] = src[i];
}

extern "C" void kernel_launch(void* const* d_in, const int* in_sizes, int n_in,
                              void* d_out, int out_size, void* d_ws, size_t ws_size,
                              hipStream_t stream) {
    const float *graph = nullptr, *adj = nullptr, *weight = nullptr, *bias = nullptr;
    for (int i = 0; i < n_in; i++) {
        const float* p = (const float*)d_in[i];
        switch (in_sizes[i]) {
            case BATCH * NN * FD: graph  = p; break;   // 4,194,304
            case NN * NN:         adj    = p; break;   // 16,777,216
            case FD * FD:         weight = p; break;   // 4,096
            case FD:              bias   = p; break;   // 64
        }
    }

    float* out0 = (float*)d_out;                       // [16,4096,64] fp32 (16.8MB)
    float* out1 = out0 + (size_t)BATCH * NN * FD;      // [4096,4096] fp32 (67MB)

    const size_t SZ_ADJB = (size_t)NN * NN * 2;            // 32 MiB
    const size_t SZ_SPT  = (size_t)CDIM * NN * 2;          // 8 MiB
    const size_t SZ_DSQ  = (size_t)NN * 4;                 // 16 KiB
    const size_t SZ_PART = (size_t)NN * CDIM * 2;          // 8.4 MiB per split (bf16)

    bf16 *adjb, *spT, *part; float *dsq;
    int nsplit, do_copy_in_prep;
    if (ws_size >= SZ_ADJB + SZ_SPT + SZ_DSQ + 4 * SZ_PART) {
        nsplit = 4; do_copy_in_prep = 1;
        char* s = (char*)d_ws;
        adjb = (bf16*)s;
        spT  = (bf16*)(s + SZ_ADJB);
        dsq  = (float*)(s + SZ_ADJB + SZ_SPT);
        part = (bf16*)(s + SZ_ADJB + SZ_SPT + SZ_DSQ);
    } else if (ws_size >= SZ_ADJB + SZ_SPT + SZ_DSQ + 2 * SZ_PART) {
        nsplit = 2; do_copy_in_prep = 1;
        char* s = (char*)d_ws;
        adjb = (bf16*)s;
        spT  = (bf16*)(s + SZ_ADJB);
        dsq  = (float*)(s + SZ_ADJB + SZ_SPT);
        part = (bf16*)(s + SZ_ADJB + SZ_SPT + SZ_DSQ);
    } else {
        // Carve: out1 = [part 4x8.4MB | adjb 32MB] (~66MB of 67MB);
        //        out0 = [spT 8MB | dsq 16KB] (consumed before k_epi writes out0).
        nsplit = 4; do_copy_in_prep = 0;
        part = (bf16*)out1;
        adjb = (bf16*)((char*)out1 + 4 * SZ_PART);
        spT  = (bf16*)out0;
        dsq  = (float*)((char*)out0 + SZ_SPT);
    }
    const int kchunk = NN / nsplit;

    hipLaunchKernelGGL(k_prep, dim3(NN), dim3(256), 0, stream,
                       adj, adjb, dsq, (float4*)out1, do_copy_in_prep);
    hipLaunchKernelGGL(k_support, dim3(16, 16), dim3(256), 0, stream,
                       graph, weight, dsq, spT);
    hipLaunchKernelGGL(k_gemm, dim3(32, 8, nsplit), dim3(256), 0, stream,
                       adjb, spT, dsq, part, kchunk);
    hipLaunchKernelGGL(k_epi, dim3(4096), dim3(256), 0, stream,
                       part, nsplit, bias, (float4*)out0);
    if (!do_copy_in_prep) {
        hipLaunchKernelGGL(k_copy, dim3(16384), dim3(256), 0, stream,
                           (const float4*)adj, (float4*)out1);
    }
}